// Round 3
// baseline (422.009 us; speedup 1.0000x reference)
//
#include <hip/hip_runtime.h>
#include <hip/hip_bf16.h>
#include <stdint.h>

#define N 8192
#define D 128
#define JSEG 512                   // sim columns per block
#define JT   16                    // cols per MFMA tile
#define JP   (JSEG / 32)           // 16 column-PAIR iterations (32 cols each)
#define IW   32                    // i-rows per wave (2 MFMA tiles stacked)
#define GRID_X (N / JSEG)          // 16
#define GRID_Y (N / 128)           // 64 (4 waves x 32 rows = 128 rows/block)

typedef __bf16 bf16x8_t __attribute__((ext_vector_type(8)));
typedef __bf16 bf16x2_t __attribute__((ext_vector_type(2)));
typedef float  f32x4_t  __attribute__((ext_vector_type(4)));

// --- Kernel 1: row-normalize embeddings, cast to bf16; zero the output ----
__global__ __launch_bounds__(256) void normalize_k(const float* __restrict__ emb,
                                                   __bf16* __restrict__ xb,
                                                   float* __restrict__ out) {
    if (blockIdx.x == 0 && threadIdx.x == 0) out[0] = 0.0f;
    const int row  = blockIdx.x * 4 + (threadIdx.x >> 6);
    const int lane = threadIdx.x & 63;
    const float2* src = reinterpret_cast<const float2*>(emb + (size_t)row * D);
    float2 v = src[lane];
    float ss = v.x * v.x + v.y * v.y;
#pragma unroll
    for (int off = 32; off; off >>= 1) ss += __shfl_xor(ss, off);
    const float inv = 1.0f / fmaxf(sqrtf(ss), 1e-8f);
    bf16x2_t o;
    o.x = (__bf16)(v.x * inv);
    o.y = (__bf16)(v.y * inv);
    *reinterpret_cast<bf16x2_t*>(xb + (size_t)row * D + lane * 2) = o;
}

// --- Kernel 2: fused GEMM + MSE, swapped operands, NT sim stream -----------
// R7 theory: sim (33.5 MB/XCD per pass) was evicting the 2 MB xb from L2,
// pushing a-frag loads to L3 and contending L2 fill ports with the sim
// stream itself (observed ~5.0 TB/s vs 6.3 achievable).
// (a) sim loads are NON-TEMPORAL (nt): they no longer allocate/displace in
//     L2, so xb stays L2-resident and a-frags are cheap L2 hits.
// (b) loop restructured to a 32-col PAIR per iteration: the even-half and
//     odd-half sim loads of each 128 B line are issued back-to-back, so the
//     full line is consumed within one issue group -> nt cannot cause
//     re-fetch even with zero retention.
// Issue order per pair: a[odd-tile] loads -> even MFMA/fmaf -> nt sim pair
// (jp+1) -> a[even-tile jp+1] loads -> odd MFMA/fmaf. The odd MFMA's vmcnt
// wait (for a[1]) leaves the 8 newer loads in flight.
__global__ __launch_bounds__(256, 4) void gemm_loss_k(const __bf16* __restrict__ xb,
                                                      const float* __restrict__ sim,
                                                      float* __restrict__ out) {
    const int lane = threadIdx.x & 63;
    const int wave = threadIdx.x >> 6;
    const int m = lane & 15;   // i-row within tile (C col); a/b frag row
    const int q = lane >> 4;   // k-quad; C row-quad (j-col quad after swap)
    const int i0 = blockIdx.y * 128 + wave * IW;
    const int j0 = blockIdx.x * JSEG;

    // Fixed B-operand frags: the wave's 32 i-rows (two 16-row sets). 32 VGPR.
    bf16x8_t bA[4], bB[4];
#pragma unroll
    for (int kk = 0; kk < 4; ++kk) {
        bA[kk] = *reinterpret_cast<const bf16x8_t*>(
            xb + (size_t)(i0 + m) * D + kk * 32 + q * 8);
        bB[kk] = *reinterpret_cast<const bf16x8_t*>(
            xb + (size_t)(i0 + 16 + m) * D + kk * 32 + q * 8);
    }

    // Per-thread sim row pointers: row i0+m (and +16), cols j0 + q*4.
    const float* simA = sim + (size_t)(i0 + m) * N + j0 + q * 4;
    const float* simB = simA + (size_t)16 * N;

    bf16x8_t a[2][4];            // a[0]=even tile, a[1]=odd tile (32 VGPR)
    f32x4_t  svA[2][2], svB[2][2]; // [pingpong][half] nt sim (32 VGPR)

    // ---- prologue: sim pair 0 (nt, full lines) + a-frags for tile 0 ----
    svA[0][0] = __builtin_nontemporal_load(reinterpret_cast<const f32x4_t*>(simA));
    svA[0][1] = __builtin_nontemporal_load(reinterpret_cast<const f32x4_t*>(simA + JT));
    svB[0][0] = __builtin_nontemporal_load(reinterpret_cast<const f32x4_t*>(simB));
    svB[0][1] = __builtin_nontemporal_load(reinterpret_cast<const f32x4_t*>(simB + JT));
#pragma unroll
    for (int kk = 0; kk < 4; ++kk)
        a[0][kk] = *reinterpret_cast<const bf16x8_t*>(
            xb + (size_t)(j0 + m) * D + kk * 32 + q * 8);

    const f32x4_t zero = {0.0f, 0.0f, 0.0f, 0.0f};
    float local = 0.0f;

#pragma unroll 2
    for (int jp = 0; jp < JP; ++jp) {
        const int cur = jp & 1, nxt = cur ^ 1;
        const int jbase = j0 + jp * 32;

        // ---- a-frags for the odd tile of this pair ----
#pragma unroll
        for (int kk = 0; kk < 4; ++kk)
            a[1][kk] = *reinterpret_cast<const bf16x8_t*>(
                xb + (size_t)(jbase + JT + m) * D + kk * 32 + q * 8);

        // ---- even tile: two 16x16 pred tiles sharing a[0] ----
        {
            f32x4_t accA = zero, accB = zero;
#pragma unroll
            for (int kk = 0; kk < 4; ++kk) {
                accA = __builtin_amdgcn_mfma_f32_16x16x32_bf16(a[0][kk], bA[kk], accA, 0, 0, 0);
                accB = __builtin_amdgcn_mfma_f32_16x16x32_bf16(a[0][kk], bB[kk], accB, 0, 0, 0);
            }
#pragma unroll
            for (int r = 0; r < 4; ++r) {
                const float dA = accA[r] - svA[cur][0][r];
                local = fmaf(dA, dA, local);
                const float dB = accB[r] - svB[cur][0][r];
                local = fmaf(dB, dB, local);
            }
        }

        if (jp + 1 < JP) {
            // ---- nt sim pair jp+1: both halves of each 128 B line,
            //      issued back-to-back ----
            const size_t o = (size_t)(jp + 1) * 32;
            svA[nxt][0] = __builtin_nontemporal_load(reinterpret_cast<const f32x4_t*>(simA + o));
            svA[nxt][1] = __builtin_nontemporal_load(reinterpret_cast<const f32x4_t*>(simA + o + JT));
            svB[nxt][0] = __builtin_nontemporal_load(reinterpret_cast<const f32x4_t*>(simB + o));
            svB[nxt][1] = __builtin_nontemporal_load(reinterpret_cast<const f32x4_t*>(simB + o + JT));
            // ---- a-frags for the next pair's even tile ----
#pragma unroll
            for (int kk = 0; kk < 4; ++kk)
                a[0][kk] = *reinterpret_cast<const bf16x8_t*>(
                    xb + (size_t)(jbase + 32 + m) * D + kk * 32 + q * 8);
        }

        // ---- odd tile: waits only for a[1]; 8 newer loads stay in flight --
        {
            f32x4_t accA = zero, accB = zero;
#pragma unroll
            for (int kk = 0; kk < 4; ++kk) {
                accA = __builtin_amdgcn_mfma_f32_16x16x32_bf16(a[1][kk], bA[kk], accA, 0, 0, 0);
                accB = __builtin_amdgcn_mfma_f32_16x16x32_bf16(a[1][kk], bB[kk], accB, 0, 0, 0);
            }
#pragma unroll
            for (int r = 0; r < 4; ++r) {
                const float dA = accA[r] - svA[cur][1][r];
                local = fmaf(dA, dA, local);
                const float dB = accB[r] - svB[cur][1][r];
                local = fmaf(dB, dB, local);
            }
        }
    }

#pragma unroll
    for (int off = 32; off; off >>= 1) local += __shfl_xor(local, off);
    __shared__ float wsum[4];
    if (lane == 0) wsum[wave] = local;
    __syncthreads();
    if (threadIdx.x == 0) {
        const float blocksum = wsum[0] + wsum[1] + wsum[2] + wsum[3];
        atomicAdd(out, blocksum * (1.0f / ((float)N * (float)N)));
    }
}

extern "C" void kernel_launch(void* const* d_in, const int* in_sizes, int n_in,
                              void* d_out, int out_size, void* d_ws, size_t ws_size,
                              hipStream_t stream) {
    const float* emb = (const float*)d_in[0];
    const float* sim = (const float*)d_in[1];
    __bf16* xb = (__bf16*)d_ws;                                   // 2 MB bf16 x

    normalize_k<<<N / 4, 256, 0, stream>>>(emb, xb, (float*)d_out);
    gemm_loss_k<<<dim3(GRID_X, GRID_Y), 256, 0, stream>>>(xb, sim, (float*)d_out);
}

// Round 4
// 383.077 us; speedup vs baseline: 1.1016x; 1.1016x over previous
//
#include <hip/hip_runtime.h>
#include <hip/hip_bf16.h>
#include <stdint.h>

#define N 8192
#define D 128
#define JSEG 512                   // sim columns per block
#define JT   16                    // cols per j-iteration
#define ITERS (JSEG / JT)          // 32
#define IW   32                    // i-rows per wave (2 MFMA tiles stacked)
#define GRID_X (N / JSEG)          // 16
#define GRID_Y (N / 128)           // 64 (4 waves x 32 rows = 128 rows/block)

typedef __bf16 bf16x8_t __attribute__((ext_vector_type(8)));
typedef __bf16 bf16x2_t __attribute__((ext_vector_type(2)));
typedef float  f32x4_t  __attribute__((ext_vector_type(4)));

// --- Kernel 1: row-normalize embeddings, cast to bf16; zero the output ----
__global__ __launch_bounds__(256) void normalize_k(const float* __restrict__ emb,
                                                   __bf16* __restrict__ xb,
                                                   float* __restrict__ out) {
    if (blockIdx.x == 0 && threadIdx.x == 0) out[0] = 0.0f;
    const int row  = blockIdx.x * 4 + (threadIdx.x >> 6);
    const int lane = threadIdx.x & 63;
    const float2* src = reinterpret_cast<const float2*>(emb + (size_t)row * D);
    float2 v = src[lane];
    float ss = v.x * v.x + v.y * v.y;
#pragma unroll
    for (int off = 32; off; off >>= 1) ss += __shfl_xor(ss, off);
    const float inv = 1.0f / fmaxf(sqrtf(ss), 1e-8f);
    bf16x2_t o;
    o.x = (__bf16)(v.x * inv);
    o.y = (__bf16)(v.y * inv);
    *reinterpret_cast<bf16x2_t*>(xb + (size_t)row * D + lane * 2) = o;
}

// --- Kernel 2: fused GEMM + MSE, swapped operands, PHASE-ROTATED j-walk ----
// R8 theory: R1/R2 structural changes were perf-identical (380.65/380.66) ->
// limiter is issue-order-insensitive. Suspect: DRAM channel aliasing. Each
// wave-load requests 16 x 64B segments at stride 32 KB (pow2) -> same-column
// offsets alias to the same HBM channel under pow2 interleave; all 4 waves
// of a block walk the same jt sequence -> only a few dozen distinct column
// offsets in flight chip-wide -> fraction of channels active (~4.9/6.3 TB/s).
// Fix: each wave starts its j-tile walk at phase jstart = ((y*4+w)*2)&31.
// Even phases keep the two 64B halves of each 128B line in adjacent
// iterations (L2 merges them; no re-fetch). Chip-wide: ~256 distinct column
// offsets in flight spanning the full 32 KB row pitch -> all channels busy.
// Loads are normal cached (nt REVERTED: it caused 2x line re-fetch, R3).
__global__ __launch_bounds__(256, 4) void gemm_loss_k(const __bf16* __restrict__ xb,
                                                      const float* __restrict__ sim,
                                                      float* __restrict__ out) {
    const int lane = threadIdx.x & 63;
    const int wave = threadIdx.x >> 6;
    const int m = lane & 15;   // i-row within tile (C col); a/b frag row
    const int q = lane >> 4;   // k-quad; C row-quad (j-col quad after swap)
    const int i0 = blockIdx.y * 128 + wave * IW;
    const int j0 = blockIdx.x * JSEG;
    // Per-wave rotation phase (even -> 128B line halves stay adjacent).
    const int jstart = (((blockIdx.y << 2) | wave) << 1) & 31;

    // Fixed B-operand frags: the wave's 32 i-rows (two 16-row sets). 32 VGPR.
    bf16x8_t bA[4], bB[4];
#pragma unroll
    for (int kk = 0; kk < 4; ++kk) {
        bA[kk] = *reinterpret_cast<const bf16x8_t*>(
            xb + (size_t)(i0 + m) * D + kk * 32 + q * 8);
        bB[kk] = *reinterpret_cast<const bf16x8_t*>(
            xb + (size_t)(i0 + 16 + m) * D + kk * 32 + q * 8);
    }

    // Per-thread sim row pointers: row i0+m (and +16), cols j0 + q*4.
    const float* simA = sim + (size_t)(i0 + m) * N + j0 + q * 4;
    const float* simB = simA + (size_t)16 * N;

    bf16x8_t a[2][4];         // ping-pong j-row frags (32 VGPR)
    f32x4_t  svA[2], svB[2];  // ping-pong sim float4s (16 VGPR)

    // ---- prologue: sim(phys 0), sim(phys 1) and a-frags(phys 0) ----
    const int p0 = jstart;                    // phys tile of jt=0
    const int p1 = (jstart + 1) & 31;         // phys tile of jt=1
    svA[0] = *reinterpret_cast<const f32x4_t*>(simA + p0 * JT);
    svB[0] = *reinterpret_cast<const f32x4_t*>(simB + p0 * JT);
    svA[1] = *reinterpret_cast<const f32x4_t*>(simA + p1 * JT);
    svB[1] = *reinterpret_cast<const f32x4_t*>(simB + p1 * JT);
#pragma unroll
    for (int kk = 0; kk < 4; ++kk)
        a[0][kk] = *reinterpret_cast<const bf16x8_t*>(
            xb + (size_t)(j0 + p0 * JT + m) * D + kk * 32 + q * 8);

    const f32x4_t zero = {0.0f, 0.0f, 0.0f, 0.0f};
    float local = 0.0f;

#pragma unroll 2
    for (int jt = 0; jt < ITERS; ++jt) {
        const int cur = jt & 1, nxt = cur ^ 1;
        // ---- prefetch a-frags for jt+1 (L2 hits, one period of flight) ----
        if (jt + 1 < ITERS) {
            const int jp = (jstart + jt + 1) & 31;
            const int j = j0 + jp * JT;
#pragma unroll
            for (int kk = 0; kk < 4; ++kk)
                a[nxt][kk] = *reinterpret_cast<const bf16x8_t*>(
                    xb + (size_t)(j + m) * D + kk * 32 + q * 8);
        }
        // ---- two 16x16 pred tiles sharing a[cur] ----
        f32x4_t accA = zero, accB = zero;
#pragma unroll
        for (int kk = 0; kk < 4; ++kk) {
            accA = __builtin_amdgcn_mfma_f32_16x16x32_bf16(a[cur][kk], bA[kk], accA, 0, 0, 0);
            accB = __builtin_amdgcn_mfma_f32_16x16x32_bf16(a[cur][kk], bB[kk], accB, 0, 0, 0);
        }
        // ---- fused (pred - sim)^2; acc[r] = pred[i0+m][j0+jp*16+q*4+r] ----
#pragma unroll
        for (int r = 0; r < 4; ++r) {
            const float dA = accA[r] - svA[cur][r];
            local = fmaf(dA, dA, local);
            const float dB = accB[r] - svB[cur][r];
            local = fmaf(dB, dB, local);
        }
        // ---- consume-then-reload: sim(jt+2) into the buffer just freed ----
        if (jt + 2 < ITERS) {
            const int jp2 = (jstart + jt + 2) & 31;
            svA[cur] = *reinterpret_cast<const f32x4_t*>(simA + jp2 * JT);
            svB[cur] = *reinterpret_cast<const f32x4_t*>(simB + jp2 * JT);
        }
    }

#pragma unroll
    for (int off = 32; off; off >>= 1) local += __shfl_xor(local, off);
    __shared__ float wsum[4];
    if (lane == 0) wsum[wave] = local;
    __syncthreads();
    if (threadIdx.x == 0) {
        const float blocksum = wsum[0] + wsum[1] + wsum[2] + wsum[3];
        atomicAdd(out, blocksum * (1.0f / ((float)N * (float)N)));
    }
}

extern "C" void kernel_launch(void* const* d_in, const int* in_sizes, int n_in,
                              void* d_out, int out_size, void* d_ws, size_t ws_size,
                              hipStream_t stream) {
    const float* emb = (const float*)d_in[0];
    const float* sim = (const float*)d_in[1];
    __bf16* xb = (__bf16*)d_ws;                                   // 2 MB bf16 x

    normalize_k<<<N / 4, 256, 0, stream>>>(emb, xb, (float*)d_out);
    gemm_loss_k<<<dim3(GRID_X, GRID_Y), 256, 0, stream>>>(xb, sim, (float*)d_out);
}

// Round 5
// 369.754 us; speedup vs baseline: 1.1413x; 1.0360x over previous
//
#include <hip/hip_runtime.h>
#include <hip/hip_bf16.h>
#include <stdint.h>

#define N 8192
#define D 128
#define JSEG 512                   // sim columns per block
#define JT   16                    // cols per j-iteration
#define ITERS (JSEG / JT)          // 32
#define IW   64                    // i-rows per wave (4 MFMA tiles stacked)
#define GRID_X (N / JSEG)          // 16 (j-windows; x-major keeps co-resident
                                   //     blocks on one CU at the same j0)
#define GRID_Y (N / 256)           // 32 (4 waves x 64 rows = 256 rows/block)

typedef __bf16 bf16x8_t __attribute__((ext_vector_type(8)));
typedef __bf16 bf16x2_t __attribute__((ext_vector_type(2)));
typedef float  f32x4_t  __attribute__((ext_vector_type(4)));

// --- Kernel 1: row-normalize embeddings, cast to bf16; zero the output ----
__global__ __launch_bounds__(256) void normalize_k(const float* __restrict__ emb,
                                                   __bf16* __restrict__ xb,
                                                   float* __restrict__ out) {
    if (blockIdx.x == 0 && threadIdx.x == 0) out[0] = 0.0f;
    const int row  = blockIdx.x * 4 + (threadIdx.x >> 6);
    const int lane = threadIdx.x & 63;
    const float2* src = reinterpret_cast<const float2*>(emb + (size_t)row * D);
    float2 v = src[lane];
    float ss = v.x * v.x + v.y * v.y;
#pragma unroll
    for (int off = 32; off; off >>= 1) ss += __shfl_xor(ss, off);
    const float inv = 1.0f / fmaxf(sqrtf(ss), 1e-8f);
    bf16x2_t o;
    o.x = (__bf16)(v.x * inv);
    o.y = (__bf16)(v.y * inv);
    *reinterpret_cast<bf16x2_t*>(xb + (size_t)row * D + lane * 2) = o;
}

// --- Kernel 2: fused GEMM + MSE, swapped operands, IW=64 -------------------
// R9 theory: R3's nt experiment proved the chip sustains 5.7 TB/s aggregate
// with this instruction structure -> R2's 5.0 TB/s sim rate is NOT a DRAM
// ceiling. The binder is the shared L1/L2 request path: per 2 KB of sim,
// R2 moved 4 KB of xb a-frags (L1-missing to L2 because the sim stream
// thrashes L1) -> 3x traffic and 3x 64B-segment requests per sim byte.
// Fix: each wave holds FOUR fixed i-row fragment sets (IW=64, 64 VGPR), so
// one a-frag load feeds 4 KB of sim -> xb:sim drops 2:1 -> 1:1, total
// request-path traffic per sim byte drops 3x -> 2x. Register-only change:
// no barriers, no LDS. ~165 VGPR -> 2 blocks/CU (8 waves), in-flight sim
// ~32 KB/CU vs ~9 KB needed for latency coverage.
// (Phase rotation from R8 reverted: neutral-to-negative.)
__global__ __launch_bounds__(256, 2) void gemm_loss_k(const __bf16* __restrict__ xb,
                                                      const float* __restrict__ sim,
                                                      float* __restrict__ out) {
    const int lane = threadIdx.x & 63;
    const int wave = threadIdx.x >> 6;
    const int m = lane & 15;   // i-row within tile (C col); a/b frag row
    const int q = lane >> 4;   // k-quad; C row-quad (j-col quad after swap)
    const int i0 = blockIdx.y * 256 + wave * IW;
    const int j0 = blockIdx.x * JSEG;

    // Fixed B-operand frags: the wave's 64 i-rows (four 16-row sets). 64 VGPR.
    bf16x8_t b[4][4];
#pragma unroll
    for (int s = 0; s < 4; ++s)
#pragma unroll
        for (int kk = 0; kk < 4; ++kk)
            b[s][kk] = *reinterpret_cast<const bf16x8_t*>(
                xb + (size_t)(i0 + s * 16 + m) * D + kk * 32 + q * 8);

    // Per-thread sim row pointers: rows i0 + s*16 + m, cols j0 + q*4.
    const float* simr[4];
#pragma unroll
    for (int s = 0; s < 4; ++s)
        simr[s] = sim + (size_t)(i0 + s * 16 + m) * N + j0 + q * 4;

    bf16x8_t a[2][4];       // ping-pong j-row frags (32 VGPR)
    f32x4_t  sv[4][2];      // [i-set][pingpong] sim float4s (32 VGPR)

    // ---- prologue: sim(0), sim(1) and a-frags(0) in flight ----
#pragma unroll
    for (int s = 0; s < 4; ++s) {
        sv[s][0] = *reinterpret_cast<const f32x4_t*>(simr[s]);
        sv[s][1] = *reinterpret_cast<const f32x4_t*>(simr[s] + JT);
    }
#pragma unroll
    for (int kk = 0; kk < 4; ++kk)
        a[0][kk] = *reinterpret_cast<const bf16x8_t*>(
            xb + (size_t)(j0 + m) * D + kk * 32 + q * 8);

    const f32x4_t zero = {0.0f, 0.0f, 0.0f, 0.0f};
    float local = 0.0f;

#pragma unroll 2
    for (int jt = 0; jt < ITERS; ++jt) {
        const int cur = jt & 1, nxt = cur ^ 1;
        // ---- prefetch a-frags for jt+1 (one period of flight) ----
        if (jt + 1 < ITERS) {
            const int j = j0 + (jt + 1) * JT;
#pragma unroll
            for (int kk = 0; kk < 4; ++kk)
                a[nxt][kk] = *reinterpret_cast<const bf16x8_t*>(
                    xb + (size_t)(j + m) * D + kk * 32 + q * 8);
        }
        // ---- four 16x16 pred tiles sharing a[cur] ----
        f32x4_t acc[4];
#pragma unroll
        for (int s = 0; s < 4; ++s) acc[s] = zero;
#pragma unroll
        for (int kk = 0; kk < 4; ++kk) {
#pragma unroll
            for (int s = 0; s < 4; ++s)
                acc[s] = __builtin_amdgcn_mfma_f32_16x16x32_bf16(a[cur][kk], b[s][kk], acc[s], 0, 0, 0);
        }
        // ---- fused (pred - sim)^2; acc[s][r] = pred[i0+s*16+m][j+q*4+r] ----
#pragma unroll
        for (int s = 0; s < 4; ++s)
#pragma unroll
            for (int r = 0; r < 4; ++r) {
                const float d = acc[s][r] - sv[s][cur][r];
                local = fmaf(d, d, local);
            }
        // ---- consume-then-reload: sim(jt+2) into the buffer just freed ----
        if (jt + 2 < ITERS) {
#pragma unroll
            for (int s = 0; s < 4; ++s)
                sv[s][cur] = *reinterpret_cast<const f32x4_t*>(
                    simr[s] + (size_t)(jt + 2) * JT);
        }
    }

#pragma unroll
    for (int off = 32; off; off >>= 1) local += __shfl_xor(local, off);
    __shared__ float wsum[4];
    if (lane == 0) wsum[wave] = local;
    __syncthreads();
    if (threadIdx.x == 0) {
        const float blocksum = wsum[0] + wsum[1] + wsum[2] + wsum[3];
        atomicAdd(out, blocksum * (1.0f / ((float)N * (float)N)));
    }
}

extern "C" void kernel_launch(void* const* d_in, const int* in_sizes, int n_in,
                              void* d_out, int out_size, void* d_ws, size_t ws_size,
                              hipStream_t stream) {
    const float* emb = (const float*)d_in[0];
    const float* sim = (const float*)d_in[1];
    __bf16* xb = (__bf16*)d_ws;                                   // 2 MB bf16 x

    normalize_k<<<N / 4, 256, 0, stream>>>(emb, xb, (float*)d_out);
    gemm_loss_k<<<dim3(GRID_X, GRID_Y), 256, 0, stream>>>(xb, sim, (float*)d_out);
}